// Round 10
// baseline (162.654 us; speedup 1.0000x reference)
//
#include <hip/hip_runtime.h>
#include <stdint.h>

typedef __bf16 bf16x8 __attribute__((ext_vector_type(8)));
typedef float f32x4 __attribute__((ext_vector_type(4)));

#define AS1 __attribute__((address_space(1)))
#define AS3 __attribute__((address_space(3)))

__device__ __forceinline__ unsigned short f2bf(float f) {
    unsigned int u = __float_as_uint(f);
    u += 0x7FFFu + ((u >> 16) & 1u);   // round-to-nearest-even (inputs are finite)
    return (unsigned short)(u >> 16);
}

__device__ __forceinline__ float wave_sum(float v) {
    #pragma unroll
    for (int off = 1; off < 64; off <<= 1) v += __shfl_xor(v, off);
    return v;
}

// global -> LDS direct DMA, 16B per lane. LDS dest must be wave-uniform base.
__device__ __forceinline__ void gload16(const void* g, void* l) {
    __builtin_amdgcn_global_load_lds(
        (AS1 void*)(uintptr_t)g,
        (AS3 void*)(unsigned int)(uintptr_t)l,
        16, 0, 0);
}

// ---------------- kernel 1: x -> bf16 + accept gate, fused Wp/Wc -> bf16 ----------------
__global__ __launch_bounds__(256) void k_gate_convert_w(
    const float* __restrict__ x, const float* __restrict__ Wg, const float* __restrict__ bg,
    const float* __restrict__ Wp, const float* __restrict__ Wc,
    unsigned short* __restrict__ x_bf, float* __restrict__ gate,
    unsigned short* __restrict__ Wp_bf, unsigned short* __restrict__ Wc_bf,
    float* __restrict__ score_acc)
{
    const int s = blockIdx.x;            // token row 0..16383
    const int t = threadIdx.x;
    if (s < 1024) {                      // weight-conversion side job
        const int i = s * 256 + t;       // x4 floats = 1M elems each
        if (i == 0) score_acc[0] = 0.0f;
        float4 a = reinterpret_cast<const float4*>(Wp)[i];
        float4 b = reinterpret_cast<const float4*>(Wc)[i];
        ushort4 ra, rb;
        ra.x = f2bf(a.x); ra.y = f2bf(a.y); ra.z = f2bf(a.z); ra.w = f2bf(a.w);
        rb.x = f2bf(b.x); rb.y = f2bf(b.y); rb.z = f2bf(b.z); rb.w = f2bf(b.w);
        reinterpret_cast<ushort4*>(Wp_bf)[i] = ra;
        reinterpret_cast<ushort4*>(Wc_bf)[i] = rb;
    }
    const size_t base = (size_t)s * 1024;
    float4 v = reinterpret_cast<const float4*>(x + base)[t];
    float4 w = reinterpret_cast<const float4*>(Wg)[t];
    ushort4 r;
    r.x = f2bf(v.x); r.y = f2bf(v.y); r.z = f2bf(v.z); r.w = f2bf(v.w);
    reinterpret_cast<ushort4*>(x_bf + base)[t] = r;
    float p = v.x*w.x + v.y*w.y + v.z*w.z + v.w*w.w;
    #pragma unroll
    for (int off = 32; off > 0; off >>= 1) p += __shfl_down(p, off);
    __shared__ float sm[4];
    if ((t & 63) == 0) sm[t >> 6] = p;
    __syncthreads();
    if (t == 0) {
        float z = sm[0] + sm[1] + sm[2] + sm[3] + bg[0];
        gate[s] = 1.0f / (1.0f + expf(-z));
    }
}

// ---------------- big GEMM: 256x256 tile, BK=64, 8 waves (2M x 4N), 128x64/wave ----
// 4-phase-per-K-tile interleaved schedule (faithful template port, 3rd attempt):
//   phase = one C-quadrant (4mi x 2ni x 2kj = 16 MFMA). Per phase:
//     [12 ds_read_b128 issued]  <- BEFORE the barrier: latency hides under barrier wait
//     [2 gload_lds: 1/4 of tile t+1]  <- staging spread across phases, not upfront
//     s_barrier ; (compiler lgkmcnt before MFMA use)
//     setprio(1) ; 16 MFMA ; setprio(0)
//     s_barrier
//   Tile boundary: vmcnt(0) (residual = only the 2 loads staged in the last phase,
//   ~400cy; counted-N is unsound here since every phase reads both staging halves
//   across the wave population) ; barrier.
// WAR: staging targets buf^1, last read in tile t-1, sealed by that tile's final
// barrier. All acc/af/bfr indices compile-time (rule #20); raw barriers are asm
// volatile + "memory" so C++ LDS ops cannot cross (rule #18 concerns inline-asm
// reads only; ds_reads here are C++ derefs with compiler-managed lgkmcnt).
// R7/R8 failures: R7 staged all-upfront + read-after-barrier (no overlap), R8
// changed tile shape. This keeps R6's proven tile/layout/swizzle/epilogue.
__global__ __launch_bounds__(512, 2) void k_gemm256(
    const unsigned short* __restrict__ A,
    const unsigned short* __restrict__ Bw,
    const float* __restrict__ bias,
    float* __restrict__ C,
    unsigned short* __restrict__ cmean)
{
    __shared__ alignas(16) unsigned char lds[131072];   // [buf][A 32K | B 32K]

    const int tid  = threadIdx.x;
    const int lane = tid & 63;
    const int w    = tid >> 6;          // wave 0..7
    const int wm   = w >> 2;            // 0..1  (128-row half)
    const int wn   = w & 3;             // 0..3  (64-col quarter)
    // XCD-aware decode: hardware round-robins flat id % 8 across XCDs.
    const int flat = blockIdx.x;        // 0..255
    const int xcd  = flat & 7;
    const int ii   = flat >> 3;         // 0..31
    const int bm   = xcd * 8 + (ii >> 2);   // 8 A-panels per XCD
    const int bn   = ii & 3;

    // staging: 8 issues per K-tile (A 4 + B 4); issue e covers rows e*64 + srow.
    // source k pre-swizzled by row&7 so the linear LDS write lands XOR-swizzled.
    const int srow    = tid >> 3;                               // 0..63
    const int kColOff = (((tid & 7) ^ (srow & 7)) << 3);        // elems
    const size_t aRowBase = (size_t)(bm * 256 + srow) * 1024;
    const size_t bRowBase = (size_t)(bn * 256 + srow) * 1024;
    const int ldsWave = w * 1024;                               // wave byte base per 8KB issue

    const int l15 = lane & 15;
    const int lq  = lane >> 4;
    const int rswz = (lane & 7) << 4;   // read-side swizzle key ((row&7)<<4)

    f32x4 acc[8][4];
    #pragma unroll
    for (int i = 0; i < 8; ++i)
        #pragma unroll
        for (int j = 0; j < 4; ++j)
            acc[i][j] = f32x4{0.f, 0.f, 0.f, 0.f};

    // ---- prologue: stage tile 0 into buf 0, full drain ----
    #pragma unroll
    for (int e = 0; e < 4; ++e) {
        gload16(A + aRowBase + (size_t)e * 65536 + kColOff, lds + e * 8192 + ldsWave);
        gload16(Bw + bRowBase + (size_t)e * 65536 + kColOff, lds + 32768 + e * 8192 + ldsWave);
    }
    asm volatile("s_waitcnt vmcnt(0)" ::: "memory");
    asm volatile("s_barrier" ::: "memory");

    #pragma unroll 1
    for (int t = 0; t < 16; ++t) {
        const unsigned char* ldsA = lds + (t & 1) * 65536;
        const unsigned char* ldsB = ldsA + 32768;
        unsigned char* dst = lds + ((t + 1) & 1) * 65536;
        const int k0n = (t + 1) * 64 + kColOff;

        #pragma unroll
        for (int ph = 0; ph < 4; ++ph) {
            const int mh = ph & 1;          // A-row half of the wave's 128
            const int nh = ph >> 1;         // B-col half of the wave's 64
            // ---- 12 ds_reads for this quadrant (before barrier) ----
            bf16x8 af[2][4], bfr[2][2];
            #pragma unroll
            for (int kj = 0; kj < 2; ++kj) {
                const int rboff = ((kj * 64 + lq * 16) ^ rswz);
                #pragma unroll
                for (int mi = 0; mi < 4; ++mi)
                    af[kj][mi] = *reinterpret_cast<const bf16x8*>(
                        ldsA + (wm*128 + mh*64 + mi*16 + l15) * 128 + rboff);
                #pragma unroll
                for (int ni = 0; ni < 2; ++ni)
                    bfr[kj][ni] = *reinterpret_cast<const bf16x8*>(
                        ldsB + (wn*64 + nh*32 + ni*16 + l15) * 128 + rboff);
            }
            // ---- stage 2 gloads of tile t+1 (A in phases 0-1, B in 2-3) ----
            if (t < 15) {
                if (ph < 2) {
                    gload16(A + aRowBase + (size_t)(2*ph)   * 65536 + k0n,
                            dst + (2*ph)   * 8192 + ldsWave);
                    gload16(A + aRowBase + (size_t)(2*ph+1) * 65536 + k0n,
                            dst + (2*ph+1) * 8192 + ldsWave);
                } else {
                    const int e = 2 * (ph - 2);
                    gload16(Bw + bRowBase + (size_t)e     * 65536 + k0n,
                            dst + 32768 + e     * 8192 + ldsWave);
                    gload16(Bw + bRowBase + (size_t)(e+1) * 65536 + k0n,
                            dst + 32768 + (e+1) * 8192 + ldsWave);
                }
            }
            asm volatile("s_barrier" ::: "memory");   // reads in flight; wait overlaps latency
            __builtin_amdgcn_s_setprio(1);
            #pragma unroll
            for (int kj = 0; kj < 2; ++kj)
                #pragma unroll
                for (int mi = 0; mi < 4; ++mi)
                    #pragma unroll
                    for (int ni = 0; ni < 2; ++ni)
                        acc[mh*4 + mi][nh*2 + ni] = __builtin_amdgcn_mfma_f32_16x16x32_bf16(
                            af[kj][mi], bfr[kj][ni], acc[mh*4 + mi][nh*2 + ni], 0, 0, 0);
            __builtin_amdgcn_s_setprio(0);
            if (ph < 3) asm volatile("s_barrier" ::: "memory");
        }
        // ---- tile boundary ----
        if (t < 15) asm volatile("s_waitcnt vmcnt(0)" ::: "memory");
        asm volatile("s_barrier" ::: "memory");
    }

    // ---- epilogue phase 1: bias add (in-place) + fused chunk means ----
    // D layout: col = lane&15, row = 4*(lane>>4)+reg.
    const int colBase = bn * 256 + wn * 64;
    #pragma unroll
    for (int ni = 0; ni < 4; ++ni) {
        const int col = colBase + ni * 16 + l15;
        const float bv = bias[col];
        #pragma unroll
        for (int mi = 0; mi < 8; ++mi) {
            f32x4 v = acc[mi][ni];
            v[0] += bv; v[1] += bv; v[2] += bv; v[3] += bv;
            acc[mi][ni] = v;
            float sgroup = v[0] + v[1] + v[2] + v[3];   // 4 rows of this lane-quad
            sgroup += __shfl_xor(sgroup, 16);           // 4 lane-quads -> 16 rows (one chunk)
            sgroup += __shfl_xor(sgroup, 32);
            if (lq == 0) {
                const int chunk = bm * 16 + wm * 8 + mi;
                cmean[(size_t)chunk * 1024 + col] = f2bf(sgroup * 0.0625f);
            }
        }
    }

    // ---- epilogue phase 2: repack C through LDS, 2 rounds x 128 rows ----
    // 256B-contiguous dword runs (tp base is 4B-odd: naive fragment stores = 2x
    // HBM write amplification).
    float* ldsC = reinterpret_cast<float*>(lds);
    #pragma unroll 1
    for (int r = 0; r < 2; ++r) {
        __syncthreads();
        if (wm == r) {
            #pragma unroll
            for (int mi = 0; mi < 8; ++mi) {
                #pragma unroll
                for (int ni = 0; ni < 4; ++ni) {
                    f32x4 v = acc[mi][ni];
                    #pragma unroll
                    for (int j = 0; j < 4; ++j) {
                        const int lrow = mi * 16 + lq * 4 + j;          // 0..127
                        const int col  = wn * 64 + ni * 16 + l15;
                        ldsC[lrow * 256 + (col ^ ((lrow & 15) << 2))] = v[j];
                    }
                }
            }
        }
        __syncthreads();
        const int gRowBase = bm * 256 + r * 128;
        #pragma unroll
        for (int rr = 0; rr < 16; ++rr) {
            const int rl = rr * 8 + w;
            const size_t gbase = (size_t)(gRowBase + rl) * 1024 + bn * 256;
            const int key = (rl & 15) << 2;
            #pragma unroll
            for (int j = 0; j < 4; ++j)
                C[gbase + j * 64 + lane] = ldsC[rl * 256 + ((j * 64 + lane) ^ key)];
        }
    }
}

// ---------------- small GEMM: 128x128 tile, double-buffered, SPLIT-K x2 ----------------
__global__ __launch_bounds__(256) void k_gemm128(
    const unsigned short* __restrict__ A,
    const unsigned short* __restrict__ Bw,
    const float* __restrict__ bias,
    float* __restrict__ C)
{
    __shared__ alignas(16) unsigned char lds[65536];    // [buf][A 16K | B 16K]

    const int tid  = threadIdx.x;
    const int lane = tid & 63;
    const int wid  = tid >> 6;
    const int wm   = wid >> 1;
    const int wn   = wid & 1;
    const int bm   = blockIdx.x;
    const int bn   = blockIdx.y;
    const int kbase = blockIdx.z * 512;   // K-half

    const int l8 = lane >> 3;
    const int kColOff = (((lane & 7) ^ l8) << 3);
    const size_t aRow = (size_t)(bm * 128 + wid * 32 + l8) * 1024;
    const size_t bRow = (size_t)(bn * 128 + wid * 32 + l8) * 1024;
    const int ldsWave = wid * 4096;

    const int l15 = lane & 15;
    const int lq  = lane >> 4;
    const int rswz = (lane & 7) << 4;

    f32x4 acc[4][4];
    #pragma unroll
    for (int i = 0; i < 4; ++i)
        #pragma unroll
        for (int j = 0; j < 4; ++j)
            acc[i][j] = f32x4{0.f, 0.f, 0.f, 0.f};

    // prologue: stage tile 0 into buf 0
    #pragma unroll
    for (int i = 0; i < 4; ++i) {
        gload16(A + aRow + (size_t)(i * 8) * 1024 + (kbase + kColOff),
                lds + ldsWave + i * 1024);
        gload16(Bw + bRow + (size_t)(i * 8) * 1024 + (kbase + kColOff),
                lds + 16384 + ldsWave + i * 1024);
    }
    __syncthreads();

    int buf = 0;
    #pragma unroll 1
    for (int t = 0; t < 8; ++t) {
        if (t < 7) {
            const int k0n = kbase + (t + 1) * 64;
            unsigned char* dst = lds + (buf ^ 1) * 32768;
            #pragma unroll
            for (int i = 0; i < 4; ++i) {
                gload16(A + aRow + (size_t)(i * 8) * 1024 + (k0n + kColOff),
                        dst + ldsWave + i * 1024);
                gload16(Bw + bRow + (size_t)(i * 8) * 1024 + (k0n + kColOff),
                        dst + 16384 + ldsWave + i * 1024);
            }
        }
        const unsigned char* ldsA = lds + buf * 32768;
        const unsigned char* ldsB = ldsA + 16384;
        #pragma unroll
        for (int kj = 0; kj < 2; ++kj) {
            const int rboff = ((kj * 64 + lq * 16) ^ rswz);
            bf16x8 af[4], bfr[4];
            #pragma unroll
            for (int mi = 0; mi < 4; ++mi)
                af[mi] = *reinterpret_cast<const bf16x8*>(ldsA + (wm*64 + mi*16 + l15) * 128 + rboff);
            #pragma unroll
            for (int ni = 0; ni < 4; ++ni)
                bfr[ni] = *reinterpret_cast<const bf16x8*>(ldsB + (wn*64 + ni*16 + l15) * 128 + rboff);
            #pragma unroll
            for (int mi = 0; mi < 4; ++mi)
                #pragma unroll
                for (int ni = 0; ni < 4; ++ni)
                    acc[mi][ni] = __builtin_amdgcn_mfma_f32_16x16x32_bf16(
                        af[mi], bfr[ni], acc[mi][ni], 0, 0, 0);
        }
        __syncthreads();
        buf ^= 1;
    }

    const int colBase = bn * 128 + wn * 64;
    const int rowBase = bm * 128 + wm * 64;
    #pragma unroll
    for (int ni = 0; ni < 4; ++ni) {
        const int col = colBase + ni * 16 + l15;
        const float bv = (blockIdx.z == 0) ? bias[col] : 0.0f;
        #pragma unroll
        for (int mi = 0; mi < 4; ++mi) {
            f32x4 v = acc[mi][ni];
            const int r0 = rowBase + mi * 16 + lq * 4;
            atomicAdd(&C[(size_t)(r0 + 0) * 1024 + col], v[0] + bv);
            atomicAdd(&C[(size_t)(r0 + 1) * 1024 + col], v[1]);
            atomicAdd(&C[(size_t)(r0 + 2) * 1024 + col], v[2]);
            atomicAdd(&C[(size_t)(r0 + 3) * 1024 + col], v[3]);
        }
    }
}

// ---------------- kernel 4: feedback + cosine similarity + score accumulate ----------
// NOTE: no __threadfence / fused finalize here — a device-scope fence per block
// forced L2 writebacks and cost ~100 µs (R5 post-mortem). Separate tiny kernel.
__global__ __launch_bounds__(256) void k_epilogue(
    const float* __restrict__ tp, const float* __restrict__ cons,
    const float* __restrict__ gate, float* __restrict__ fb,
    float* __restrict__ score_acc)
{
    const int chunk = blockIdx.x;           // 0..1023
    const int lane  = threadIdx.x & 63;
    const int w     = threadIdx.x >> 6;     // wave 0..3, each handles 4 tokens
    const size_t cbase = (size_t)chunk * 1024 + lane * 16;

    float cvl[16];
    #pragma unroll
    for (int q = 0; q < 4; ++q) {
        float4 cq = reinterpret_cast<const float4*>(cons + cbase)[q];
        cvl[q*4+0] = cq.x; cvl[q*4+1] = cq.y; cvl[q*4+2] = cq.z; cvl[q*4+3] = cq.w;
    }
    float ncs = 0.f;
    #pragma unroll
    for (int j = 0; j < 16; ++j) ncs += cvl[j] * cvl[j];
    ncs = wave_sum(ncs);
    const float cnorm = fmaxf(sqrtf(ncs), 1e-8f);

    float local = 0.f;
    #pragma unroll
    for (int i = 0; i < 4; ++i) {
        const int s = chunk * 16 + w * 4 + i;
        const float g = gate[s];
        const float* tr = tp + (size_t)s * 1024 + lane * 16;   // odd base -> scalar loads
        float* fr = fb + (size_t)s * 1024 + lane * 16;         // aligned -> float4 stores
        float num = 0.f, ntp = 0.f;
        #pragma unroll
        for (int j = 0; j < 16; ++j) {
            const float tv = tr[j];
            num += tv * cvl[j];
            ntp += tv * tv;
        }
        #pragma unroll
        for (int q = 0; q < 4; ++q) {
            float4 fo;
            fo.x = g * cvl[q*4+0]; fo.y = g * cvl[q*4+1];
            fo.z = g * cvl[q*4+2]; fo.w = g * cvl[q*4+3];
            reinterpret_cast<float4*>(fr)[q] = fo;
        }
        num = wave_sum(num);
        ntp = wave_sum(ntp);
        if (lane == 0) local += num / (fmaxf(sqrtf(ntp), 1e-8f) * cnorm);
    }

    __shared__ float sm[4];
    if (lane == 0) sm[w] = local;
    __syncthreads();
    if (threadIdx.x == 0)
        atomicAdd(score_acc, sm[0] + sm[1] + sm[2] + sm[3]);
}

__global__ void k_finalize(const float* __restrict__ acc, float* __restrict__ out) {
    out[0] = acc[0] * (1.0f / 16384.0f);
}

extern "C" void kernel_launch(void* const* d_in, const int* in_sizes, int n_in,
                              void* d_out, int out_size, void* d_ws, size_t ws_size,
                              hipStream_t stream)
{
    (void)in_sizes; (void)n_in; (void)out_size; (void)ws_size;
    const float* x  = (const float*)d_in[0];
    const float* Wp = (const float*)d_in[1];
    const float* bp = (const float*)d_in[2];
    const float* Wc = (const float*)d_in[3];
    const float* bc = (const float*)d_in[4];
    const float* Wg = (const float*)d_in[5];
    const float* bg = (const float*)d_in[6];
    float* out = (float*)d_out;

    unsigned char* ws = (unsigned char*)d_ws;
    unsigned short* x_bf  = (unsigned short*)(ws);               // 32 MiB
    unsigned short* Wp_bf = (unsigned short*)(ws + 33554432);    // 2 MiB
    unsigned short* Wc_bf = (unsigned short*)(ws + 35651584);    // 2 MiB
    unsigned short* cmean = (unsigned short*)(ws + 37748736);    // 2 MiB
    float* gate      = (float*)(ws + 39845888);                  // 64 KiB
    float* score_acc = (float*)(ws + 39911424);                  // 4 B

    // output regions (floats): pc | feedback | score | token_proposals
    float* pc = out;                  // [4*256,1024]
    float* fb = out + 1048576;        // [4*4096,1024]
    float* sc = out + 17825792;       // [1]
    float* tp = out + 17825793;       // [4*4096,1024]  (odd offset: scalar access only)

    hipMemsetAsync(pc, 0, 4194304, stream);   // zero pc for split-K atomics
    k_gate_convert_w<<<16384, 256, 0, stream>>>(x, Wg, bg, Wp, Wc,
                                                x_bf, gate, Wp_bf, Wc_bf, score_acc);
    k_gemm256<<<256, 512, 0, stream>>>(x_bf, Wp_bf, bp, tp, cmean);
    k_gemm128<<<dim3(8, 8, 2), 256, 0, stream>>>(cmean, Wc_bf, bc, pc);
    k_epilogue<<<1024, 256, 0, stream>>>(tp, pc, gate, fb, score_acc);
    k_finalize<<<1, 1, 0, stream>>>(score_acc, sc);
}

// Round 11
// 108.796 us; speedup vs baseline: 1.4950x; 1.4950x over previous
//
#include <hip/hip_runtime.h>
#include <stdint.h>

typedef __bf16 bf16x8 __attribute__((ext_vector_type(8)));
typedef float f32x4 __attribute__((ext_vector_type(4)));

#define AS1 __attribute__((address_space(1)))
#define AS3 __attribute__((address_space(3)))

__device__ __forceinline__ unsigned short f2bf(float f) {
    unsigned int u = __float_as_uint(f);
    u += 0x7FFFu + ((u >> 16) & 1u);   // round-to-nearest-even (inputs are finite)
    return (unsigned short)(u >> 16);
}

__device__ __forceinline__ float wave_sum(float v) {
    #pragma unroll
    for (int off = 1; off < 64; off <<= 1) v += __shfl_xor(v, off);
    return v;
}

// global -> LDS direct DMA, 16B per lane. LDS dest must be wave-uniform base.
__device__ __forceinline__ void gload16(const void* g, void* l) {
    __builtin_amdgcn_global_load_lds(
        (AS1 void*)(uintptr_t)g,
        (AS3 void*)(unsigned int)(uintptr_t)l,
        16, 0, 0);
}

// ---------------- kernel 1: x -> bf16 + accept gate, fused Wp/Wc -> bf16 ----------------
__global__ __launch_bounds__(256) void k_gate_convert_w(
    const float* __restrict__ x, const float* __restrict__ Wg, const float* __restrict__ bg,
    const float* __restrict__ Wp, const float* __restrict__ Wc,
    unsigned short* __restrict__ x_bf, float* __restrict__ gate,
    unsigned short* __restrict__ Wp_bf, unsigned short* __restrict__ Wc_bf,
    float* __restrict__ score_acc)
{
    const int s = blockIdx.x;            // token row 0..16383
    const int t = threadIdx.x;
    if (s < 1024) {                      // weight-conversion side job
        const int i = s * 256 + t;       // x4 floats = 1M elems each
        if (i == 0) score_acc[0] = 0.0f;
        float4 a = reinterpret_cast<const float4*>(Wp)[i];
        float4 b = reinterpret_cast<const float4*>(Wc)[i];
        ushort4 ra, rb;
        ra.x = f2bf(a.x); ra.y = f2bf(a.y); ra.z = f2bf(a.z); ra.w = f2bf(a.w);
        rb.x = f2bf(b.x); rb.y = f2bf(b.y); rb.z = f2bf(b.z); rb.w = f2bf(b.w);
        reinterpret_cast<ushort4*>(Wp_bf)[i] = ra;
        reinterpret_cast<ushort4*>(Wc_bf)[i] = rb;
    }
    const size_t base = (size_t)s * 1024;
    float4 v = reinterpret_cast<const float4*>(x + base)[t];
    float4 w = reinterpret_cast<const float4*>(Wg)[t];
    ushort4 r;
    r.x = f2bf(v.x); r.y = f2bf(v.y); r.z = f2bf(v.z); r.w = f2bf(v.w);
    reinterpret_cast<ushort4*>(x_bf + base)[t] = r;
    float p = v.x*w.x + v.y*w.y + v.z*w.z + v.w*w.w;
    #pragma unroll
    for (int off = 32; off > 0; off >>= 1) p += __shfl_down(p, off);
    __shared__ float sm[4];
    if ((t & 63) == 0) sm[t >> 6] = p;
    __syncthreads();
    if (t == 0) {
        float z = sm[0] + sm[1] + sm[2] + sm[3] + bg[0];
        gate[s] = 1.0f / (1.0f + expf(-z));
    }
}

// ---------------- big GEMM: 256x256 tile, BK=64, 16 waves (4M x 4N), 64x64/wave ----
// Best-measured structure (R6/R9, ~50us, 682 TF = the 2-phase structural ceiling):
// double-buffered LDS (2x64KB), one __syncthreads per K-step, STAGE(next) issued
// before ds_read+MFMA of current, global_load_lds both operands with pre-swizzled
// source (rule #21), acc[4][4] static-indexed (rule #20), C repacked through LDS
// into 256B-contiguous runs (tp base is 4B-odd: naive fragment stores caused 2x
// HBM write amplification). XCD-aware block decode.
// SCHEDULE NOTE (R7/R8/R10 post-mortems): three phase-split / counted-vmcnt ports
// (coarse 4-phase, triple-buffer dist-2, fine 4-phase interleave) all measured
// ~2x SLOWER (96-109us vs ~50). At 1 block/CU the extra barriers serialize;
// partial 8-phase ports are null-to-negative (m196). Do not re-attempt without
// the exact m201 template.
__global__ __launch_bounds__(1024, 4) void k_gemm256(
    const unsigned short* __restrict__ A,
    const unsigned short* __restrict__ Bw,
    const float* __restrict__ bias,
    float* __restrict__ C,
    unsigned short* __restrict__ cmean)
{
    __shared__ alignas(16) unsigned char lds[131072];   // [buf][A 32K | B 32K]

    const int tid  = threadIdx.x;
    const int lane = tid & 63;
    const int w    = tid >> 6;          // wave 0..15
    const int wm   = w >> 2;            // 0..3  (64-row band)
    const int wn   = w & 3;             // 0..3  (64-col band)
    // XCD-aware decode: hardware round-robins flat id % 8 across XCDs.
    const int flat = blockIdx.x;        // 0..255
    const int xcd  = flat & 7;
    const int ii   = flat >> 3;         // 0..31
    const int bm   = xcd * 8 + (ii >> 2);   // 8 A-panels per XCD
    const int bn   = ii & 3;

    // staging: 2 issues each for A and B; issue i covers rows i*128 + srow.
    // source k pre-swizzled by row&7 so linear LDS write lands XOR-swizzled.
    const int srow    = tid >> 3;                               // 0..127
    const int kColOff = (((tid & 7) ^ (srow & 7)) << 3);        // elems
    const size_t aRowBase = (size_t)(bm * 256 + srow) * 1024;
    const size_t bRowBase = (size_t)(bn * 256 + srow) * 1024;
    const int ldsIssue = w * 1024;                              // wave byte base per issue

    const int l15 = lane & 15;
    const int lq  = lane >> 4;
    const int rswz = (lane & 7) << 4;   // read-side swizzle key ((row&7)<<4)

    f32x4 acc[4][4];
    #pragma unroll
    for (int i = 0; i < 4; ++i)
        #pragma unroll
        for (int j = 0; j < 4; ++j)
            acc[i][j] = f32x4{0.f, 0.f, 0.f, 0.f};

    // ---- prologue: stage tile 0 into buf 0 ----
    #pragma unroll
    for (int i = 0; i < 2; ++i) {
        gload16(A + aRowBase + (size_t)i * 131072 + kColOff,
                lds + i * 16384 + ldsIssue);
        gload16(Bw + bRowBase + (size_t)i * 131072 + kColOff,
                lds + 32768 + i * 16384 + ldsIssue);
    }
    __syncthreads();                    // vmcnt(0) drained by compiler before barrier

    int buf = 0;
    #pragma unroll 1
    for (int t = 0; t < 16; ++t) {
        if (t < 15) {
            const int k0n = (t + 1) * 64;
            unsigned char* dst = lds + (buf ^ 1) * 65536;
            #pragma unroll
            for (int i = 0; i < 2; ++i) {
                gload16(A + aRowBase + (size_t)i * 131072 + (k0n + kColOff),
                        dst + i * 16384 + ldsIssue);
                gload16(Bw + bRowBase + (size_t)i * 131072 + (k0n + kColOff),
                        dst + 32768 + i * 16384 + ldsIssue);
            }
        }
        const unsigned char* ldsA = lds + buf * 65536;
        const unsigned char* ldsB = ldsA + 32768;
        #pragma unroll
        for (int kj = 0; kj < 2; ++kj) {
            const int rboff = ((kj * 64 + lq * 16) ^ rswz);
            bf16x8 af[4], bfr[4];
            #pragma unroll
            for (int mi = 0; mi < 4; ++mi)
                af[mi] = *reinterpret_cast<const bf16x8*>(ldsA + (wm*64 + mi*16 + l15) * 128 + rboff);
            #pragma unroll
            for (int ni = 0; ni < 4; ++ni)
                bfr[ni] = *reinterpret_cast<const bf16x8*>(ldsB + (wn*64 + ni*16 + l15) * 128 + rboff);
            #pragma unroll
            for (int mi = 0; mi < 4; ++mi)
                #pragma unroll
                for (int ni = 0; ni < 4; ++ni)
                    acc[mi][ni] = __builtin_amdgcn_mfma_f32_16x16x32_bf16(
                        af[mi], bfr[ni], acc[mi][ni], 0, 0, 0);
        }
        __syncthreads();                // next buffer staged; current reads done
        buf ^= 1;
    }

    // ---- epilogue phase 1: bias add (in-place) + fused chunk means ----
    // D layout: col = lane&15, row = 4*(lane>>4)+reg.
    const int colBase = bn * 256 + wn * 64;
    #pragma unroll
    for (int ni = 0; ni < 4; ++ni) {
        const int col = colBase + ni * 16 + l15;
        const float bv = bias[col];
        #pragma unroll
        for (int mi = 0; mi < 4; ++mi) {
            f32x4 v = acc[mi][ni];
            v[0] += bv; v[1] += bv; v[2] += bv; v[3] += bv;
            acc[mi][ni] = v;
            float sgroup = v[0] + v[1] + v[2] + v[3];   // 4 rows of this lane-quad
            sgroup += __shfl_xor(sgroup, 16);           // 4 lane-quads -> 16 rows (one chunk)
            sgroup += __shfl_xor(sgroup, 32);
            if (lq == 0) {
                const int chunk = bm * 16 + wm * 4 + mi;
                cmean[(size_t)chunk * 1024 + col] = f2bf(sgroup * 0.0625f);
            }
        }
    }

    // ---- epilogue phase 2: repack C through LDS, 2 rounds x 128 rows ----
    float* ldsC = reinterpret_cast<float*>(lds);
    #pragma unroll 1
    for (int r = 0; r < 2; ++r) {
        __syncthreads();                 // prior round's LDS reads done
        if ((wm >> 1) == r) {
            #pragma unroll
            for (int mi = 0; mi < 4; ++mi) {
                #pragma unroll
                for (int ni = 0; ni < 4; ++ni) {
                    f32x4 v = acc[mi][ni];
                    #pragma unroll
                    for (int j = 0; j < 4; ++j) {
                        const int lrow = (wm & 1) * 64 + mi * 16 + lq * 4 + j;
                        const int col  = wn * 64 + ni * 16 + l15;
                        ldsC[lrow * 256 + (col ^ ((lrow & 15) << 2))] = v[j];
                    }
                }
            }
        }
        __syncthreads();
        const int gRowBase = bm * 256 + r * 128;
        #pragma unroll
        for (int rr = 0; rr < 8; ++rr) {
            const int rl = rr * 16 + w;
            const size_t gbase = (size_t)(gRowBase + rl) * 1024 + bn * 256;
            const int key = (rl & 15) << 2;
            #pragma unroll
            for (int j = 0; j < 4; ++j)
                C[gbase + j * 64 + lane] = ldsC[rl * 256 + ((j * 64 + lane) ^ key)];
        }
    }
}

// ---------------- small GEMM: 128x128 tile, double-buffered, SPLIT-K x2 ----------------
__global__ __launch_bounds__(256) void k_gemm128(
    const unsigned short* __restrict__ A,
    const unsigned short* __restrict__ Bw,
    const float* __restrict__ bias,
    float* __restrict__ C)
{
    __shared__ alignas(16) unsigned char lds[65536];    // [buf][A 16K | B 16K]

    const int tid  = threadIdx.x;
    const int lane = tid & 63;
    const int wid  = tid >> 6;
    const int wm   = wid >> 1;
    const int wn   = wid & 1;
    const int bm   = blockIdx.x;
    const int bn   = blockIdx.y;
    const int kbase = blockIdx.z * 512;   // K-half

    const int l8 = lane >> 3;
    const int kColOff = (((lane & 7) ^ l8) << 3);
    const size_t aRow = (size_t)(bm * 128 + wid * 32 + l8) * 1024;
    const size_t bRow = (size_t)(bn * 128 + wid * 32 + l8) * 1024;
    const int ldsWave = wid * 4096;

    const int l15 = lane & 15;
    const int lq  = lane >> 4;
    const int rswz = (lane & 7) << 4;

    f32x4 acc[4][4];
    #pragma unroll
    for (int i = 0; i < 4; ++i)
        #pragma unroll
        for (int j = 0; j < 4; ++j)
            acc[i][j] = f32x4{0.f, 0.f, 0.f, 0.f};

    // prologue: stage tile 0 into buf 0
    #pragma unroll
    for (int i = 0; i < 4; ++i) {
        gload16(A + aRow + (size_t)(i * 8) * 1024 + (kbase + kColOff),
                lds + ldsWave + i * 1024);
        gload16(Bw + bRow + (size_t)(i * 8) * 1024 + (kbase + kColOff),
                lds + 16384 + ldsWave + i * 1024);
    }
    __syncthreads();

    int buf = 0;
    #pragma unroll 1
    for (int t = 0; t < 8; ++t) {
        if (t < 7) {
            const int k0n = kbase + (t + 1) * 64;
            unsigned char* dst = lds + (buf ^ 1) * 32768;
            #pragma unroll
            for (int i = 0; i < 4; ++i) {
                gload16(A + aRow + (size_t)(i * 8) * 1024 + (k0n + kColOff),
                        dst + ldsWave + i * 1024);
                gload16(Bw + bRow + (size_t)(i * 8) * 1024 + (k0n + kColOff),
                        dst + 16384 + ldsWave + i * 1024);
            }
        }
        const unsigned char* ldsA = lds + buf * 32768;
        const unsigned char* ldsB = ldsA + 16384;
        #pragma unroll
        for (int kj = 0; kj < 2; ++kj) {
            const int rboff = ((kj * 64 + lq * 16) ^ rswz);
            bf16x8 af[4], bfr[4];
            #pragma unroll
            for (int mi = 0; mi < 4; ++mi)
                af[mi] = *reinterpret_cast<const bf16x8*>(ldsA + (wm*64 + mi*16 + l15) * 128 + rboff);
            #pragma unroll
            for (int ni = 0; ni < 4; ++ni)
                bfr[ni] = *reinterpret_cast<const bf16x8*>(ldsB + (wn*64 + ni*16 + l15) * 128 + rboff);
            #pragma unroll
            for (int mi = 0; mi < 4; ++mi)
                #pragma unroll
                for (int ni = 0; ni < 4; ++ni)
                    acc[mi][ni] = __builtin_amdgcn_mfma_f32_16x16x32_bf16(
                        af[mi], bfr[ni], acc[mi][ni], 0, 0, 0);
        }
        __syncthreads();
        buf ^= 1;
    }

    const int colBase = bn * 128 + wn * 64;
    const int rowBase = bm * 128 + wm * 64;
    #pragma unroll
    for (int ni = 0; ni < 4; ++ni) {
        const int col = colBase + ni * 16 + l15;
        const float bv = (blockIdx.z == 0) ? bias[col] : 0.0f;
        #pragma unroll
        for (int mi = 0; mi < 4; ++mi) {
            f32x4 v = acc[mi][ni];
            const int r0 = rowBase + mi * 16 + lq * 4;
            atomicAdd(&C[(size_t)(r0 + 0) * 1024 + col], v[0] + bv);
            atomicAdd(&C[(size_t)(r0 + 1) * 1024 + col], v[1]);
            atomicAdd(&C[(size_t)(r0 + 2) * 1024 + col], v[2]);
            atomicAdd(&C[(size_t)(r0 + 3) * 1024 + col], v[3]);
        }
    }
}

// ---------------- kernel 4: feedback + cosine similarity + score accumulate ----------
// NOTE: no __threadfence / fused finalize here — a device-scope fence per block
// forced L2 writebacks and cost ~100 µs (R5 post-mortem). Separate tiny kernel.
__global__ __launch_bounds__(256) void k_epilogue(
    const float* __restrict__ tp, const float* __restrict__ cons,
    const float* __restrict__ gate, float* __restrict__ fb,
    float* __restrict__ score_acc)
{
    const int chunk = blockIdx.x;           // 0..1023
    const int lane  = threadIdx.x & 63;
    const int w     = threadIdx.x >> 6;     // wave 0..3, each handles 4 tokens
    const size_t cbase = (size_t)chunk * 1024 + lane * 16;

    float cvl[16];
    #pragma unroll
    for (int q = 0; q < 4; ++q) {
        float4 cq = reinterpret_cast<const float4*>(cons + cbase)[q];
        cvl[q*4+0] = cq.x; cvl[q*4+1] = cq.y; cvl[q*4+2] = cq.z; cvl[q*4+3] = cq.w;
    }
    float ncs = 0.f;
    #pragma unroll
    for (int j = 0; j < 16; ++j) ncs += cvl[j] * cvl[j];
    ncs = wave_sum(ncs);
    const float cnorm = fmaxf(sqrtf(ncs), 1e-8f);

    float local = 0.f;
    #pragma unroll
    for (int i = 0; i < 4; ++i) {
        const int s = chunk * 16 + w * 4 + i;
        const float g = gate[s];
        const float* tr = tp + (size_t)s * 1024 + lane * 16;   // odd base -> scalar loads
        float* fr = fb + (size_t)s * 1024 + lane * 16;         // aligned -> float4 stores
        float num = 0.f, ntp = 0.f;
        #pragma unroll
        for (int j = 0; j < 16; ++j) {
            const float tv = tr[j];
            num += tv * cvl[j];
            ntp += tv * tv;
        }
        #pragma unroll
        for (int q = 0; q < 4; ++q) {
            float4 fo;
            fo.x = g * cvl[q*4+0]; fo.y = g * cvl[q*4+1];
            fo.z = g * cvl[q*4+2]; fo.w = g * cvl[q*4+3];
            reinterpret_cast<float4*>(fr)[q] = fo;
        }
        num = wave_sum(num);
        ntp = wave_sum(ntp);
        if (lane == 0) local += num / (fmaxf(sqrtf(ntp), 1e-8f) * cnorm);
    }

    __shared__ float sm[4];
    if (lane == 0) sm[w] = local;
    __syncthreads();
    if (threadIdx.x == 0)
        atomicAdd(score_acc, sm[0] + sm[1] + sm[2] + sm[3]);
}

__global__ void k_finalize(const float* __restrict__ acc, float* __restrict__ out) {
    out[0] = acc[0] * (1.0f / 16384.0f);
}

extern "C" void kernel_launch(void* const* d_in, const int* in_sizes, int n_in,
                              void* d_out, int out_size, void* d_ws, size_t ws_size,
                              hipStream_t stream)
{
    (void)in_sizes; (void)n_in; (void)out_size; (void)ws_size;
    const float* x  = (const float*)d_in[0];
    const float* Wp = (const float*)d_in[1];
    const float* bp = (const float*)d_in[2];
    const float* Wc = (const float*)d_in[3];
    const float* bc = (const float*)d_in[4];
    const float* Wg = (const float*)d_in[5];
    const float* bg = (const float*)d_in[6];
    float* out = (float*)d_out;

    unsigned char* ws = (unsigned char*)d_ws;
    unsigned short* x_bf  = (unsigned short*)(ws);               // 32 MiB
    unsigned short* Wp_bf = (unsigned short*)(ws + 33554432);    // 2 MiB
    unsigned short* Wc_bf = (unsigned short*)(ws + 35651584);    // 2 MiB
    unsigned short* cmean = (unsigned short*)(ws + 37748736);    // 2 MiB
    float* gate      = (float*)(ws + 39845888);                  // 64 KiB
    float* score_acc = (float*)(ws + 39911424);                  // 4 B

    // output regions (floats): pc | feedback | score | token_proposals
    float* pc = out;                  // [4*256,1024]
    float* fb = out + 1048576;        // [4*4096,1024]
    float* sc = out + 17825792;       // [1]
    float* tp = out + 17825793;       // [4*4096,1024]  (odd offset: scalar access only)

    hipMemsetAsync(pc, 0, 4194304, stream);   // zero pc for split-K atomics
    k_gate_convert_w<<<16384, 256, 0, stream>>>(x, Wg, bg, Wp, Wc,
                                                x_bf, gate, Wp_bf, Wc_bf, score_acc);
    k_gemm256<<<256, 1024, 0, stream>>>(x_bf, Wp_bf, bp, tp, cmean);
    k_gemm128<<<dim3(8, 8, 2), 256, 0, stream>>>(cmean, Wc_bf, bc, pc);
    k_epilogue<<<1024, 256, 0, stream>>>(tp, pc, gate, fb, score_acc);
    k_finalize<<<1, 1, 0, stream>>>(score_acc, sc);
}